// Round 12
// baseline (104.056 us; speedup 1.0000x reference)
//
#include <hip/hip_runtime.h>
#include <math.h>

// Problem constants (from reference)
#define N_Q 4096
#define M_K 8192
#define D_DIM 512
#define P_IDX 4
#define INV_TEMP 10.0f

#define NCHUNK 256          // 8192 cols / 32-col (interleaved) chunks

typedef __attribute__((ext_vector_type(4))) _Float16 f16x4;
typedef __attribute__((ext_vector_type(8))) _Float16 f16x8;
typedef __attribute__((ext_vector_type(16))) float f32x16;

// ---------------------------------------------------------------------------
// Convert fp32 -> fp16 (RN), Q and K fused in one launch.
// Q is pre-scaled by INV_TEMP so the GEMM directly yields scores/TEMP.
// ---------------------------------------------------------------------------
__global__ __launch_bounds__(256)
void conv_f16(const float* __restrict__ Q, const float* __restrict__ K,
              _Float16* __restrict__ h, int nq4, int ntot4)
{
    int i = blockIdx.x * 256 + threadIdx.x;
    if (i >= ntot4) return;
    const bool isq = (i < nq4);
    float4 v = isq ? ((const float4*)Q)[i] : ((const float4*)K)[i - nq4];
    const float sc = isq ? INV_TEMP : 1.0f;
    f16x4 o;
    o.x = (_Float16)(v.x * sc); o.y = (_Float16)(v.y * sc);
    o.z = (_Float16)(v.z * sc); o.w = (_Float16)(v.w * sc);
    ((f16x4*)h)[i] = o;
}

__device__ __forceinline__ void gload16(const void* g, const void* l) {
    __builtin_amdgcn_global_load_lds(
        (const __attribute__((address_space(1))) unsigned int*)g,
        (__attribute__((address_space(3))) unsigned int*)l, 16, 0, 0);
}

// ---------------------------------------------------------------------------
// SWAPPED single-pass fp16 MFMA GEMM: scores^T = MFMA(K, Q); lane axis =
// Q-row, register pattern = K-col -> pure in-lane epilogue (no shuffles).
// 256(K) x 128(Q) tile, BK=32, 8 waves (4 wr x 2 wc), 32x32x16_f16,
// double-buffered 2x24 KB staging, one barrier per K-step.  48 KB LDS +
// ~124 unified regs -> 2 blocks/CU (16 waves TLP), half the barrier events
// and -25% L2 staging traffic vs the 128x128 variant.
// Grid (32 kTiles, 32 qTiles) natural order, block 512.
// ---------------------------------------------------------------------------
__global__ __launch_bounds__(512, 4)
void scores_mfma(const _Float16* __restrict__ Qh, const _Float16* __restrict__ Kh,
                 const int* __restrict__ ign, float4* __restrict__ part)
{
    // buffer layout (f16 units): K-plane [oct 0..3][row 0..255][8] = 8192,
    // Q-plane at +8192: [oct 0..3][row 0..127][8] = 4096.  24 KB per buffer.
    __shared__ __align__(16) _Float16 smem[2][12288];

    const int tid = threadIdx.x;          // 0..511
    const int lane = tid & 63;
    const int wave = tid >> 6;            // 0..7
    const int wr = wave >> 1;             // 0..3  K-row quadrant
    const int wc = wave & 1;              // 0..1  Q-col half
    const int hi = lane >> 5, lx = lane & 31;
    const int bx = blockIdx.x;            // K-tile index (32)
    const int by = blockIdx.y;            // Q-tile index (32)
    const int krow0 = bx * 256;
    const int qrow0 = by * 128;

    // 3 staging streams per thread: 2 K-chunks + 1 Q-chunk (16 B each)
    const _Float16* srcs[3];
    int dsts[3];
#pragma unroll
    for (int it = 0; it < 3; ++it) {
        if (it < 2) {
            const int c = it * 512 + tid;         // K chunk 0..1023
            const int oct = c >> 8, r = c & 255;
            srcs[it] = Kh + (size_t)(krow0 + r) * D_DIM + oct * 8;
            dsts[it] = c * 8;
        } else {
            const int c = tid;                    // Q chunk 0..511
            const int oct = c >> 7, r = c & 127;
            srcs[it] = Qh + (size_t)(qrow0 + r) * D_DIM + oct * 8;
            dsts[it] = 8192 + c * 8;
        }
    }

    f32x16 acc[2][2];
#pragma unroll
    for (int i = 0; i < 2; ++i)
#pragma unroll
        for (int j = 0; j < 2; ++j) acc[i][j] = (f32x16)0.f;

    // prologue: stage K-tile 0 into buffer 0
#pragma unroll
    for (int it = 0; it < 3; ++it)
        gload16(srcs[it], &smem[0][dsts[it]]);
    __syncthreads();        // buf0 fully staged (drains vmcnt, all waves)

    for (int t = 0; t < 16; ++t) {
        const int cur = t & 1;
        // prefetch tile t+1 first -> L2 latency hides under this iteration
        if (t < 15) {
            const int k0 = (t + 1) * 32;
#pragma unroll
            for (int it = 0; it < 3; ++it)
                gload16(srcs[it] + k0, &smem[cur ^ 1][dsts[it]]);
        }

        const _Float16* sbuf = smem[cur];
        f16x8 a[2][2], b[2][2];
#pragma unroll
        for (int ks = 0; ks < 2; ++ks) {
            const int oct = ks * 2 + hi;
#pragma unroll
            for (int i = 0; i < 2; ++i) {
                const int oa = (oct * 256 + wr * 64 + i * 32 + lx) * 8;   // K plane
                a[i][ks] = *(const f16x8*)&sbuf[oa];
            }
#pragma unroll
            for (int j = 0; j < 2; ++j) {
                const int ob = 8192 + (oct * 128 + wc * 64 + j * 32 + lx) * 8; // Q
                b[j][ks] = *(const f16x8*)&sbuf[ob];
            }
        }
#pragma unroll
        for (int ks = 0; ks < 2; ++ks)
#pragma unroll
            for (int i = 0; i < 2; ++i)
#pragma unroll
                for (int j = 0; j < 2; ++j)
                    acc[i][j] = __builtin_amdgcn_mfma_f32_32x32x16_f16(a[i][ks], b[j][ks], acc[i][j], 0, 0, 0);

        __syncthreads();    // buf[cur] free + buf[cur^1] staged
    }

    // Epilogue (all in-lane):
    //   acc[i][j][r] = score(qrow = qrow0 + wc*64 + j*32 + lx,
    //                        kcol = krow0 + wr*64 + i*32 + (r&3)+8*(r>>2)+4*hi)
    const int kbase = krow0 + wr * 64 + 4 * hi;
    const int chunk = bx * 8 + wr * 2 + hi;       // 0..255
#pragma unroll
    for (int j = 0; j < 2; ++j) {
        const int qrow = qrow0 + wc * 64 + j * 32 + lx;
        const int4 ig = ((const int4*)ign)[qrow];   // 4 ignore indices, 16B
        float bm = -INFINITY; int bi = 0x7fffffff;
        // pass 1: mask -> write back into acc; running max/argmax
#pragma unroll
        for (int i = 0; i < 2; ++i) {
#pragma unroll
            for (int r = 0; r < 16; ++r) {
                const int col = kbase + i * 32 + (r & 3) + 8 * (r >> 2);
                float x = acc[i][j][r];
                if (col == ig.x || col == ig.y || col == ig.z || col == ig.w)
                    x = -INFINITY;
                acc[i][j][r] = x;
                if (x > bm || (x == bm && col < bi)) { bm = x; bi = col; }
            }
        }
        // pass 2: sumexp
        float se = 0.f;
#pragma unroll
        for (int i = 0; i < 2; ++i)
#pragma unroll
            for (int r = 0; r < 16; ++r)
                se += __expf(acc[i][j][r] - bm);
        part[(size_t)qrow * NCHUNK + chunk] =
            make_float4(bm, se, __int_as_float(bi), 0.f);
    }
}

// ---------------------------------------------------------------------------
// Kernel B: one wave per row.  Merge 256 chunk partials -> lse + argmax;
// positives recomputed EXACTLY in fp32 (with duplicate dedup).
// ---------------------------------------------------------------------------
__global__ __launch_bounds__(64)
void combine_kernel(const float4* __restrict__ part,
                    const float* __restrict__ Q, const float* __restrict__ K,
                    const int* __restrict__ pos,
                    float* __restrict__ logp, float* __restrict__ corrects)
{
    const int row = blockIdx.x;
    const int lane = threadIdx.x;

    float4 p0 = part[(size_t)row * NCHUNK + lane];
    float m = p0.x, s = p0.y, av = p0.x;
    int ai = __float_as_int(p0.z);
#pragma unroll
    for (int k = 1; k < 4; ++k) {
        float4 p = part[(size_t)row * NCHUNK + k * 64 + lane];
        int oi = __float_as_int(p.z);
        float nm = fmaxf(m, p.x);
        s = s * expf(m - nm) + p.y * expf(p.x - nm);
        m = nm;
        if (p.x > av || (p.x == av && oi < ai)) { av = p.x; ai = oi; }
    }

#pragma unroll
    for (int off = 32; off >= 1; off >>= 1) {
        float om = __shfl_xor(m, off);
        float os = __shfl_xor(s, off);
        float oav = __shfl_xor(av, off);
        int oi = __shfl_xor(ai, off);
        float nm = fmaxf(m, om);
        s = s * expf(m - nm) + os * expf(om - nm);
        m = nm;
        if (oav > av || (oav == av && oi < ai)) { av = oav; ai = oi; }
    }
    float lse = m + logf(s);

    int pi[4];
#pragma unroll
    for (int p = 0; p < 4; ++p) pi[p] = pos[row * P_IDX + p];

    // positive dot-products in exact fp32: lane covers 8 consecutive d-elements
    const float4* q4 = (const float4*)(Q + (size_t)row * D_DIM);
    float4 qa = q4[lane * 2], qb = q4[lane * 2 + 1];
    float d[4];
#pragma unroll
    for (int p = 0; p < 4; ++p) {
        const float4* k4 = (const float4*)(K + (size_t)pi[p] * D_DIM);
        float4 ka = k4[lane * 2], kb = k4[lane * 2 + 1];
        d[p] = qa.x * ka.x + qa.y * ka.y + qa.z * ka.z + qa.w * ka.w
             + qb.x * kb.x + qb.y * kb.y + qb.z * kb.z + qb.w * kb.w;
    }
#pragma unroll
    for (int off = 32; off >= 1; off >>= 1) {
#pragma unroll
        for (int p = 0; p < 4; ++p) d[p] += __shfl_xor(d[p], off);
    }

    if (lane == 0) {
        float ps[4];
#pragma unroll
        for (int p = 0; p < 4; ++p) ps[p] = d[p] * INV_TEMP;
        const bool v1 = (pi[1] != pi[0]);
        const bool v2 = (pi[2] != pi[0]) && (pi[2] != pi[1]);
        const bool v3 = (pi[3] != pi[0]) && (pi[3] != pi[1]) && (pi[3] != pi[2]);
        float pm = ps[0];
        if (v1) pm = fmaxf(pm, ps[1]);
        if (v2) pm = fmaxf(pm, ps[2]);
        if (v3) pm = fmaxf(pm, ps[3]);
        float pse = expf(ps[0] - pm);
        if (v1) pse += expf(ps[1] - pm);
        if (v2) pse += expf(ps[2] - pm);
        if (v3) pse += expf(ps[3] - pm);
        float pos_lse = pm + logf(pse);
        logp[row] = pos_lse - lse;
        bool corr = (ai == pi[0]) || (ai == pi[1]) || (ai == pi[2]) || (ai == pi[3]);
        corrects[row] = corr ? 1.0f : 0.0f;
    }
}

// ---------------------------------------------------------------------------
// Kernel C: deterministic fixed-order reduction of logp -> loss
// ---------------------------------------------------------------------------
__global__ __launch_bounds__(256)
void loss_kernel(const float* __restrict__ logp, float* __restrict__ out)
{
    __shared__ float sm[256];
    const int t = threadIdx.x;
    float s = 0.f;
    for (int i = t; i < N_Q; i += 256) s += logp[i];
    sm[t] = s;
    __syncthreads();
    for (int off = 128; off >= 1; off >>= 1) {
        if (t < off) sm[t] += sm[t + off];
        __syncthreads();
    }
    if (t == 0) out[0] = -sm[0];
}

// ---------------------------------------------------------------------------
extern "C" void kernel_launch(void* const* d_in, const int* in_sizes, int n_in,
                              void* d_out, int out_size, void* d_ws, size_t ws_size,
                              hipStream_t stream)
{
    const float* Q = (const float*)d_in[0];
    const float* K = (const float*)d_in[1];
    const int* pos = (const int*)d_in[2];
    const int* ign = (const int*)d_in[3];
    float* out = (float*)d_out;

    // workspace layout (total ~28 MB)
    _Float16* Qh = (_Float16*)d_ws;                              // 4 MB
    _Float16* Kh = Qh + (size_t)N_Q * D_DIM;                     // 8 MB
    float4* part = (float4*)(Kh + (size_t)M_K * D_DIM);          // 16 MB
    float* logp = (float*)(part + (size_t)N_Q * NCHUNK);         // 16 KB

    const int nq4 = N_Q * D_DIM / 4;
    const int ntot4 = (N_Q + M_K) * D_DIM / 4;
    conv_f16<<<(ntot4 + 255) / 256, 256, 0, stream>>>(Q, K, Qh, nq4, ntot4);

    dim3 gridA(M_K / 256, N_Q / 128);   // 32 kTiles x 32 qTiles
    scores_mfma<<<gridA, 512, 0, stream>>>(Qh, Kh, ign, part);
    combine_kernel<<<N_Q, 64, 0, stream>>>(part, Q, K, pos, logp, out + 1);
    loss_kernel<<<1, 256, 0, stream>>>(logp, out);
}

// Round 13
// 85.940 us; speedup vs baseline: 1.2108x; 1.2108x over previous
//
#include <hip/hip_runtime.h>
#include <math.h>

// Problem constants (from reference)
#define N_Q 4096
#define M_K 8192
#define D_DIM 512
#define P_IDX 4
#define INV_TEMP 10.0f

#define NCHUNK 256          // 8192 cols / 32-col (interleaved) chunks

typedef __attribute__((ext_vector_type(8))) _Float16 f16x8;
typedef __attribute__((ext_vector_type(16))) float f32x16;

// ---------------------------------------------------------------------------
// Pack fp32 row-major [nrows][512] into MFMA-fragment-ordered fp16:
// 16B chunk index  c = ((rb*32 + ks)*2 + hi)*32 + lx
//   holds rows rb*32+lx, k = (ks*2+hi)*8 .. +8   (scaled, RN-converted).
// A wave's 32x32x16 MFMA fragment (row=lx, k-oct=hi) for (rb, ks) is then
// the contiguous 1 KB at chunk (rb*32+ks)*64 + lane -> perfectly coalesced.
// One wave per (rb, ks) unit; reads are 64B-line-complete (hi pairs).
// ---------------------------------------------------------------------------
__global__ __launch_bounds__(256)
void pack_f16(const float* __restrict__ X, _Float16* __restrict__ P,
              int nwunits, float scale)
{
    const int wunit = blockIdx.x * 4 + (threadIdx.x >> 6);
    if (wunit >= nwunits) return;
    const int rb = wunit >> 5, ks = wunit & 31;
    const int lane = threadIdx.x & 63;
    const int hi = lane >> 5, lx = lane & 31;
    const int row = rb * 32 + lx;
    const float4* src = (const float4*)(X + (size_t)row * D_DIM + ks * 16 + hi * 8);
    float4 v0 = src[0], v1 = src[1];
    f16x8 o;
    o[0] = (_Float16)(v0.x * scale); o[1] = (_Float16)(v0.y * scale);
    o[2] = (_Float16)(v0.z * scale); o[3] = (_Float16)(v0.w * scale);
    o[4] = (_Float16)(v1.x * scale); o[5] = (_Float16)(v1.y * scale);
    o[6] = (_Float16)(v1.z * scale); o[7] = (_Float16)(v1.w * scale);
    ((f16x8*)P)[(size_t)wunit * 64 + lane] = o;
}

// ---------------------------------------------------------------------------
// LDS-free, barrier-free swapped fp16 MFMA GEMM: scores^T = MFMA(K, Q).
// Each wave streams its pre-packed fragments directly L2->regs (4 coalesced
// 16B loads per K-step, depth-1 prefetch) and issues 4 MFMAs; no staging,
// no __syncthreads.  16 waves/CU hide L2 latency by interleave.
// Lane axis = Q-row, register pattern = K-col -> pure in-lane epilogue.
// 128(K) x 128(Q) tile, 4 waves (2 wr x 2 wc), acc[2][2] f32x16.
// Grid (64 kTiles, 32 qTiles), block 256.
// ---------------------------------------------------------------------------
__global__ __launch_bounds__(256, 4)
void scores_mfma(const _Float16* __restrict__ Qp, const _Float16* __restrict__ Kp,
                 const int* __restrict__ ign, float4* __restrict__ part)
{
    const int tid = threadIdx.x;          // 0..255
    const int lane = tid & 63;
    const int wave = tid >> 6;            // 0..3
    const int wr = wave >> 1, wc = wave & 1;
    const int hi = lane >> 5, lx = lane & 31;
    const int bx = blockIdx.x;            // K-tile (128 rows), 0..63
    const int by = blockIdx.y;            // Q-tile (128 rows), 0..31

    const f16x8* Kp8 = (const f16x8*)Kp;
    const f16x8* Qp8 = (const f16x8*)Qp;
    // fragment streams: chunk (rb*32 + ks)*64 + lane, stride 64 chunks per ks
    const f16x8* A0p = Kp8 + ((size_t)(bx * 4 + wr * 2 + 0) * 32) * 64 + lane;
    const f16x8* A1p = Kp8 + ((size_t)(bx * 4 + wr * 2 + 1) * 32) * 64 + lane;
    const f16x8* B0p = Qp8 + ((size_t)(by * 4 + wc * 2 + 0) * 32) * 64 + lane;
    const f16x8* B1p = Qp8 + ((size_t)(by * 4 + wc * 2 + 1) * 32) * 64 + lane;

    f32x16 acc[2][2];
#pragma unroll
    for (int i = 0; i < 2; ++i)
#pragma unroll
        for (int j = 0; j < 2; ++j) acc[i][j] = (f32x16)0.f;

    // depth-1 software pipeline: load ks+1 while MFMA-ing ks
    f16x8 cA0 = A0p[0], cA1 = A1p[0], cB0 = B0p[0], cB1 = B1p[0];
    for (int ks = 0; ks < 32; ++ks) {
        f16x8 nA0 = cA0, nA1 = cA1, nB0 = cB0, nB1 = cB1;
        if (ks < 31) {
            const int o = (ks + 1) * 64;
            nA0 = A0p[o]; nA1 = A1p[o];
            nB0 = B0p[o]; nB1 = B1p[o];
        }
        acc[0][0] = __builtin_amdgcn_mfma_f32_32x32x16_f16(cA0, cB0, acc[0][0], 0, 0, 0);
        acc[0][1] = __builtin_amdgcn_mfma_f32_32x32x16_f16(cA0, cB1, acc[0][1], 0, 0, 0);
        acc[1][0] = __builtin_amdgcn_mfma_f32_32x32x16_f16(cA1, cB0, acc[1][0], 0, 0, 0);
        acc[1][1] = __builtin_amdgcn_mfma_f32_32x32x16_f16(cA1, cB1, acc[1][1], 0, 0, 0);
        cA0 = nA0; cA1 = nA1; cB0 = nB0; cB1 = nB1;
    }

    // Epilogue (all in-lane, R11-verified):
    //   acc[i][j][r] = score(qrow = by*128 + wc*64 + j*32 + lx,
    //                        kcol = bx*128 + wr*64 + i*32 + (r&3)+8*(r>>2)+4*hi)
    const int kbase = bx * 128 + wr * 64 + 4 * hi;
    const int chunk = bx * 4 + wr * 2 + hi;       // 0..255
#pragma unroll
    for (int j = 0; j < 2; ++j) {
        const int qrow = by * 128 + wc * 64 + j * 32 + lx;
        const int4 ig = ((const int4*)ign)[qrow];   // 4 ignore indices, 16B
        float bm = -INFINITY; int bi = 0x7fffffff;
        // pass 1: mask -> write back into acc; running max/argmax
#pragma unroll
        for (int i = 0; i < 2; ++i) {
#pragma unroll
            for (int r = 0; r < 16; ++r) {
                const int col = kbase + i * 32 + (r & 3) + 8 * (r >> 2);
                float x = acc[i][j][r];
                if (col == ig.x || col == ig.y || col == ig.z || col == ig.w)
                    x = -INFINITY;
                acc[i][j][r] = x;
                if (x > bm || (x == bm && col < bi)) { bm = x; bi = col; }
            }
        }
        // pass 2: sumexp
        float se = 0.f;
#pragma unroll
        for (int i = 0; i < 2; ++i)
#pragma unroll
            for (int r = 0; r < 16; ++r)
                se += __expf(acc[i][j][r] - bm);
        part[(size_t)qrow * NCHUNK + chunk] =
            make_float4(bm, se, __int_as_float(bi), 0.f);
    }
}

// ---------------------------------------------------------------------------
// Kernel B: one wave per row.  Merge 256 chunk partials -> lse + argmax;
// positives recomputed EXACTLY in fp32 (with duplicate dedup).
// ---------------------------------------------------------------------------
__global__ __launch_bounds__(64)
void combine_kernel(const float4* __restrict__ part,
                    const float* __restrict__ Q, const float* __restrict__ K,
                    const int* __restrict__ pos,
                    float* __restrict__ logp, float* __restrict__ corrects)
{
    const int row = blockIdx.x;
    const int lane = threadIdx.x;

    float4 p0 = part[(size_t)row * NCHUNK + lane];
    float m = p0.x, s = p0.y, av = p0.x;
    int ai = __float_as_int(p0.z);
#pragma unroll
    for (int k = 1; k < 4; ++k) {
        float4 p = part[(size_t)row * NCHUNK + k * 64 + lane];
        int oi = __float_as_int(p.z);
        float nm = fmaxf(m, p.x);
        s = s * expf(m - nm) + p.y * expf(p.x - nm);
        m = nm;
        if (p.x > av || (p.x == av && oi < ai)) { av = p.x; ai = oi; }
    }

#pragma unroll
    for (int off = 32; off >= 1; off >>= 1) {
        float om = __shfl_xor(m, off);
        float os = __shfl_xor(s, off);
        float oav = __shfl_xor(av, off);
        int oi = __shfl_xor(ai, off);
        float nm = fmaxf(m, om);
        s = s * expf(m - nm) + os * expf(om - nm);
        m = nm;
        if (oav > av || (oav == av && oi < ai)) { av = oav; ai = oi; }
    }
    float lse = m + logf(s);

    int pi[4];
#pragma unroll
    for (int p = 0; p < 4; ++p) pi[p] = pos[row * P_IDX + p];

    // positive dot-products in exact fp32: lane covers 8 consecutive d-elements
    const float4* q4 = (const float4*)(Q + (size_t)row * D_DIM);
    float4 qa = q4[lane * 2], qb = q4[lane * 2 + 1];
    float d[4];
#pragma unroll
    for (int p = 0; p < 4; ++p) {
        const float4* k4 = (const float4*)(K + (size_t)pi[p] * D_DIM);
        float4 ka = k4[lane * 2], kb = k4[lane * 2 + 1];
        d[p] = qa.x * ka.x + qa.y * ka.y + qa.z * ka.z + qa.w * ka.w
             + qb.x * kb.x + qb.y * kb.y + qb.z * kb.z + qb.w * kb.w;
    }
#pragma unroll
    for (int off = 32; off >= 1; off >>= 1) {
#pragma unroll
        for (int p = 0; p < 4; ++p) d[p] += __shfl_xor(d[p], off);
    }

    if (lane == 0) {
        float ps[4];
#pragma unroll
        for (int p = 0; p < 4; ++p) ps[p] = d[p] * INV_TEMP;
        const bool v1 = (pi[1] != pi[0]);
        const bool v2 = (pi[2] != pi[0]) && (pi[2] != pi[1]);
        const bool v3 = (pi[3] != pi[0]) && (pi[3] != pi[1]) && (pi[3] != pi[2]);
        float pm = ps[0];
        if (v1) pm = fmaxf(pm, ps[1]);
        if (v2) pm = fmaxf(pm, ps[2]);
        if (v3) pm = fmaxf(pm, ps[3]);
        float pse = expf(ps[0] - pm);
        if (v1) pse += expf(ps[1] - pm);
        if (v2) pse += expf(ps[2] - pm);
        if (v3) pse += expf(ps[3] - pm);
        float pos_lse = pm + logf(pse);
        logp[row] = pos_lse - lse;
        bool corr = (ai == pi[0]) || (ai == pi[1]) || (ai == pi[2]) || (ai == pi[3]);
        corrects[row] = corr ? 1.0f : 0.0f;
    }
}

// ---------------------------------------------------------------------------
// Kernel C: deterministic fixed-order reduction of logp -> loss
// ---------------------------------------------------------------------------
__global__ __launch_bounds__(256)
void loss_kernel(const float* __restrict__ logp, float* __restrict__ out)
{
    __shared__ float sm[256];
    const int t = threadIdx.x;
    float s = 0.f;
    for (int i = t; i < N_Q; i += 256) s += logp[i];
    sm[t] = s;
    __syncthreads();
    for (int off = 128; off >= 1; off >>= 1) {
        if (t < off) sm[t] += sm[t + off];
        __syncthreads();
    }
    if (t == 0) out[0] = -sm[0];
}

// ---------------------------------------------------------------------------
extern "C" void kernel_launch(void* const* d_in, const int* in_sizes, int n_in,
                              void* d_out, int out_size, void* d_ws, size_t ws_size,
                              hipStream_t stream)
{
    const float* Q = (const float*)d_in[0];
    const float* K = (const float*)d_in[1];
    const int* pos = (const int*)d_in[2];
    const int* ign = (const int*)d_in[3];
    float* out = (float*)d_out;

    // workspace layout (total ~28 MB)
    _Float16* Qp = (_Float16*)d_ws;                              // 4 MB
    _Float16* Kp = Qp + (size_t)N_Q * D_DIM;                     // 8 MB
    float4* part = (float4*)(Kp + (size_t)M_K * D_DIM);          // 16 MB
    float* logp = (float*)(part + (size_t)N_Q * NCHUNK);         // 16 KB

    const int qw = (N_Q / 32) * 32;       // 4096 wave-units
    const int kw = (M_K / 32) * 32;       // 8192 wave-units
    pack_f16<<<qw / 4, 256, 0, stream>>>(Q, Qp, qw, INV_TEMP);
    pack_f16<<<kw / 4, 256, 0, stream>>>(K, Kp, kw, 1.0f);

    dim3 gridA(M_K / 128, N_Q / 128);   // 64 kTiles x 32 qTiles
    scores_mfma<<<gridA, 256, 0, stream>>>(Qp, Kp, ign, part);
    combine_kernel<<<N_Q, 64, 0, stream>>>(part, Q, K, pos, logp, out + 1);
    loss_kernel<<<1, 256, 0, stream>>>(logp, out);
}

// Round 14
// 75.483 us; speedup vs baseline: 1.3785x; 1.1385x over previous
//
#include <hip/hip_runtime.h>
#include <math.h>

// Problem constants (from reference)
#define N_Q 4096
#define M_K 8192
#define D_DIM 512
#define P_IDX 4
#define INV_TEMP 10.0f

#define NCHUNK 256          // 8192 cols / 32-col (interleaved) chunks

typedef __attribute__((ext_vector_type(8))) _Float16 f16x8;
typedef __attribute__((ext_vector_type(16))) float f32x16;

// ---------------------------------------------------------------------------
// Pack fp32 row-major [nrows][512] into MFMA-fragment-ordered fp16 (Q and K
// fused in one launch; Q pre-scaled by INV_TEMP).
// 16B chunk index  c = ((rb*32 + ks)*2 + hi)*32 + lx
//   holds row rb*32+lx, k = (ks*2+hi)*8 .. +8.
// A wave's 32x32x16 fragment for (rb, ks) is the contiguous 1 KB at chunk
// (rb*32+ks)*64 + lane -> perfectly coalesced stream.
// ---------------------------------------------------------------------------
__global__ __launch_bounds__(256)
void pack_f16(const float* __restrict__ Q, const float* __restrict__ K,
              _Float16* __restrict__ Pq, _Float16* __restrict__ Pk,
              int qunits, int totunits)
{
    const int wunit = blockIdx.x * 4 + (threadIdx.x >> 6);
    if (wunit >= totunits) return;
    const bool isq = (wunit < qunits);
    const int u = isq ? wunit : wunit - qunits;
    const float* X = isq ? Q : K;
    _Float16* P = isq ? Pq : Pk;
    const float scale = isq ? INV_TEMP : 1.0f;
    const int rb = u >> 5, ks = u & 31;
    const int lane = threadIdx.x & 63;
    const int hi = lane >> 5, lx = lane & 31;
    const int row = rb * 32 + lx;
    const float4* src = (const float4*)(X + (size_t)row * D_DIM + ks * 16 + hi * 8);
    float4 v0 = src[0], v1 = src[1];
    f16x8 o;
    o[0] = (_Float16)(v0.x * scale); o[1] = (_Float16)(v0.y * scale);
    o[2] = (_Float16)(v0.z * scale); o[3] = (_Float16)(v0.w * scale);
    o[4] = (_Float16)(v1.x * scale); o[5] = (_Float16)(v1.y * scale);
    o[6] = (_Float16)(v1.z * scale); o[7] = (_Float16)(v1.w * scale);
    ((f16x8*)P)[(size_t)u * 64 + lane] = o;
}

// ---------------------------------------------------------------------------
// LDS-free, barrier-free swapped fp16 MFMA GEMM: scores^T = MFMA(K, Q).
// Fragments stream L2->regs via a 2-step unrolled PING-PONG pipeline:
// even steps consume set P (and reload P for ks+2), odd steps consume set Q
// (reload for ks+3) -> no register copies, natural s_waitcnt vmcnt(4), a
// full 2-phase latency window.  setprio(1) around MFMA quartets (independent
// -wave regime).  Lane axis = Q-row, reg pattern = K-col -> in-lane epilogue.
// 128(K) x 128(Q) tile, 4 waves (2 wr x 2 wc), acc[2][2] f32x16.
// Grid (64 kTiles, 32 qTiles), block 256.
// ---------------------------------------------------------------------------
__global__ __launch_bounds__(256, 4)
void scores_mfma(const _Float16* __restrict__ Qp, const _Float16* __restrict__ Kp,
                 const int* __restrict__ ign, float4* __restrict__ part)
{
    const int tid = threadIdx.x;          // 0..255
    const int lane = tid & 63;
    const int wave = tid >> 6;            // 0..3
    const int wr = wave >> 1, wc = wave & 1;
    const int hi = lane >> 5, lx = lane & 31;
    const int bx = blockIdx.x;            // K-tile (128 rows), 0..63
    const int by = blockIdx.y;            // Q-tile (128 rows), 0..31

    const f16x8* Kp8 = (const f16x8*)Kp;
    const f16x8* Qp8 = (const f16x8*)Qp;
    const f16x8* A0p = Kp8 + ((size_t)(bx * 4 + wr * 2 + 0) * 32) * 64 + lane;
    const f16x8* A1p = Kp8 + ((size_t)(bx * 4 + wr * 2 + 1) * 32) * 64 + lane;
    const f16x8* B0p = Qp8 + ((size_t)(by * 4 + wc * 2 + 0) * 32) * 64 + lane;
    const f16x8* B1p = Qp8 + ((size_t)(by * 4 + wc * 2 + 1) * 32) * 64 + lane;

    f32x16 acc[2][2];
#pragma unroll
    for (int i = 0; i < 2; ++i)
#pragma unroll
        for (int j = 0; j < 2; ++j) acc[i][j] = (f32x16)0.f;

    // prologue: sets for ks=0 (P) and ks=1 (Q)
    f16x8 pA0 = A0p[0],  pA1 = A1p[0],  pB0 = B0p[0],  pB1 = B1p[0];
    f16x8 qA0 = A0p[64], qA1 = A1p[64], qB0 = B0p[64], qB1 = B1p[64];

    for (int ks = 0; ks < 32; ks += 2) {
        // even phase: consume P (= ks); reload P for ks+2
        __builtin_amdgcn_s_setprio(1);
        acc[0][0] = __builtin_amdgcn_mfma_f32_32x32x16_f16(pA0, pB0, acc[0][0], 0, 0, 0);
        acc[0][1] = __builtin_amdgcn_mfma_f32_32x32x16_f16(pA0, pB1, acc[0][1], 0, 0, 0);
        acc[1][0] = __builtin_amdgcn_mfma_f32_32x32x16_f16(pA1, pB0, acc[1][0], 0, 0, 0);
        acc[1][1] = __builtin_amdgcn_mfma_f32_32x32x16_f16(pA1, pB1, acc[1][1], 0, 0, 0);
        __builtin_amdgcn_s_setprio(0);
        if (ks + 2 < 32) {
            const int o = (ks + 2) * 64;
            pA0 = A0p[o]; pA1 = A1p[o]; pB0 = B0p[o]; pB1 = B1p[o];
        }
        // odd phase: consume Q (= ks+1); reload Q for ks+3
        __builtin_amdgcn_s_setprio(1);
        acc[0][0] = __builtin_amdgcn_mfma_f32_32x32x16_f16(qA0, qB0, acc[0][0], 0, 0, 0);
        acc[0][1] = __builtin_amdgcn_mfma_f32_32x32x16_f16(qA0, qB1, acc[0][1], 0, 0, 0);
        acc[1][0] = __builtin_amdgcn_mfma_f32_32x32x16_f16(qA1, qB0, acc[1][0], 0, 0, 0);
        acc[1][1] = __builtin_amdgcn_mfma_f32_32x32x16_f16(qA1, qB1, acc[1][1], 0, 0, 0);
        __builtin_amdgcn_s_setprio(0);
        if (ks + 3 < 32) {
            const int o = (ks + 3) * 64;
            qA0 = A0p[o]; qA1 = A1p[o]; qB0 = B0p[o]; qB1 = B1p[o];
        }
    }

    // Epilogue (all in-lane, R11-verified):
    //   acc[i][j][r] = score(qrow = by*128 + wc*64 + j*32 + lx,
    //                        kcol = bx*128 + wr*64 + i*32 + (r&3)+8*(r>>2)+4*hi)
    const int kbase = bx * 128 + wr * 64 + 4 * hi;
    const int chunk = bx * 4 + wr * 2 + hi;       // 0..255
#pragma unroll
    for (int j = 0; j < 2; ++j) {
        const int qrow = by * 128 + wc * 64 + j * 32 + lx;
        const int4 ig = ((const int4*)ign)[qrow];   // 4 ignore indices, 16B
        float bm = -INFINITY; int bi = 0x7fffffff;
#pragma unroll
        for (int i = 0; i < 2; ++i) {
#pragma unroll
            for (int r = 0; r < 16; ++r) {
                const int col = kbase + i * 32 + (r & 3) + 8 * (r >> 2);
                float x = acc[i][j][r];
                if (col == ig.x || col == ig.y || col == ig.z || col == ig.w)
                    x = -INFINITY;
                acc[i][j][r] = x;
                if (x > bm || (x == bm && col < bi)) { bm = x; bi = col; }
            }
        }
        float se = 0.f;
#pragma unroll
        for (int i = 0; i < 2; ++i)
#pragma unroll
            for (int r = 0; r < 16; ++r)
                se += __expf(acc[i][j][r] - bm);
        part[(size_t)qrow * NCHUNK + chunk] =
            make_float4(bm, se, __int_as_float(bi), 0.f);
    }
}

// ---------------------------------------------------------------------------
// Kernel B: one wave per row.  Merge 256 chunk partials -> lse + argmax;
// positives recomputed EXACTLY in fp32 (with duplicate dedup).
// ---------------------------------------------------------------------------
__global__ __launch_bounds__(64)
void combine_kernel(const float4* __restrict__ part,
                    const float* __restrict__ Q, const float* __restrict__ K,
                    const int* __restrict__ pos,
                    float* __restrict__ logp, float* __restrict__ corrects)
{
    const int row = blockIdx.x;
    const int lane = threadIdx.x;

    float4 p0 = part[(size_t)row * NCHUNK + lane];
    float m = p0.x, s = p0.y, av = p0.x;
    int ai = __float_as_int(p0.z);
#pragma unroll
    for (int k = 1; k < 4; ++k) {
        float4 p = part[(size_t)row * NCHUNK + k * 64 + lane];
        int oi = __float_as_int(p.z);
        float nm = fmaxf(m, p.x);
        s = s * expf(m - nm) + p.y * expf(p.x - nm);
        m = nm;
        if (p.x > av || (p.x == av && oi < ai)) { av = p.x; ai = oi; }
    }

#pragma unroll
    for (int off = 32; off >= 1; off >>= 1) {
        float om = __shfl_xor(m, off);
        float os = __shfl_xor(s, off);
        float oav = __shfl_xor(av, off);
        int oi = __shfl_xor(ai, off);
        float nm = fmaxf(m, om);
        s = s * expf(m - nm) + os * expf(om - nm);
        m = nm;
        if (oav > av || (oav == av && oi < ai)) { av = oav; ai = oi; }
    }
    float lse = m + logf(s);

    int pi[4];
#pragma unroll
    for (int p = 0; p < 4; ++p) pi[p] = pos[row * P_IDX + p];

    // positive dot-products in exact fp32: lane covers 8 consecutive d-elements
    const float4* q4 = (const float4*)(Q + (size_t)row * D_DIM);
    float4 qa = q4[lane * 2], qb = q4[lane * 2 + 1];
    float d[4];
#pragma unroll
    for (int p = 0; p < 4; ++p) {
        const float4* k4 = (const float4*)(K + (size_t)pi[p] * D_DIM);
        float4 ka = k4[lane * 2], kb = k4[lane * 2 + 1];
        d[p] = qa.x * ka.x + qa.y * ka.y + qa.z * ka.z + qa.w * ka.w
             + qb.x * kb.x + qb.y * kb.y + qb.z * kb.z + qb.w * kb.w;
    }
#pragma unroll
    for (int off = 32; off >= 1; off >>= 1) {
#pragma unroll
        for (int p = 0; p < 4; ++p) d[p] += __shfl_xor(d[p], off);
    }

    if (lane == 0) {
        float ps[4];
#pragma unroll
        for (int p = 0; p < 4; ++p) ps[p] = d[p] * INV_TEMP;
        const bool v1 = (pi[1] != pi[0]);
        const bool v2 = (pi[2] != pi[0]) && (pi[2] != pi[1]);
        const bool v3 = (pi[3] != pi[0]) && (pi[3] != pi[1]) && (pi[3] != pi[2]);
        float pm = ps[0];
        if (v1) pm = fmaxf(pm, ps[1]);
        if (v2) pm = fmaxf(pm, ps[2]);
        if (v3) pm = fmaxf(pm, ps[3]);
        float pse = expf(ps[0] - pm);
        if (v1) pse += expf(ps[1] - pm);
        if (v2) pse += expf(ps[2] - pm);
        if (v3) pse += expf(ps[3] - pm);
        float pos_lse = pm + logf(pse);
        logp[row] = pos_lse - lse;
        bool corr = (ai == pi[0]) || (ai == pi[1]) || (ai == pi[2]) || (ai == pi[3]);
        corrects[row] = corr ? 1.0f : 0.0f;
    }
}

// ---------------------------------------------------------------------------
// Kernel C: deterministic fixed-order reduction of logp -> loss
// ---------------------------------------------------------------------------
__global__ __launch_bounds__(256)
void loss_kernel(const float* __restrict__ logp, float* __restrict__ out)
{
    __shared__ float sm[256];
    const int t = threadIdx.x;
    float s = 0.f;
    for (int i = t; i < N_Q; i += 256) s += logp[i];
    sm[t] = s;
    __syncthreads();
    for (int off = 128; off >= 1; off >>= 1) {
        if (t < off) sm[t] += sm[t + off];
        __syncthreads();
    }
    if (t == 0) out[0] = -sm[0];
}

// ---------------------------------------------------------------------------
extern "C" void kernel_launch(void* const* d_in, const int* in_sizes, int n_in,
                              void* d_out, int out_size, void* d_ws, size_t ws_size,
                              hipStream_t stream)
{
    const float* Q = (const float*)d_in[0];
    const float* K = (const float*)d_in[1];
    const int* pos = (const int*)d_in[2];
    const int* ign = (const int*)d_in[3];
    float* out = (float*)d_out;

    // workspace layout (total ~28 MB)
    _Float16* Qp = (_Float16*)d_ws;                              // 4 MB
    _Float16* Kp = Qp + (size_t)N_Q * D_DIM;                     // 8 MB
    float4* part = (float4*)(Kp + (size_t)M_K * D_DIM);          // 16 MB
    float* logp = (float*)(part + (size_t)N_Q * NCHUNK);         // 16 KB

    const int qunits = N_Q / 32 * 32;     // 4096
    const int totunits = qunits + M_K / 32 * 32;   // 12288
    pack_f16<<<totunits / 4, 256, 0, stream>>>(Q, K, Qp, Kp, qunits, totunits);

    dim3 gridA(M_K / 128, N_Q / 128);   // 64 kTiles x 32 qTiles
    scores_mfma<<<gridA, 256, 0, stream>>>(Qp, Kp, ign, part);
    combine_kernel<<<N_Q, 64, 0, stream>>>(part, Q, K, pos, logp, out + 1);
    loss_kernel<<<1, 256, 0, stream>>>(logp, out);
}

// Round 15
// 75.379 us; speedup vs baseline: 1.3804x; 1.0014x over previous
//
#include <hip/hip_runtime.h>
#include <math.h>

// Problem constants (from reference)
#define N_Q 4096
#define M_K 8192
#define D_DIM 512
#define P_IDX 4
#define INV_TEMP 10.0f

#define NCHUNK 256          // 8192 cols / 32-col (interleaved) chunks

typedef __attribute__((ext_vector_type(8))) _Float16 f16x8;
typedef __attribute__((ext_vector_type(16))) float f32x16;

// ---------------------------------------------------------------------------
// Pack fp32 row-major [nrows][512] into MFMA-fragment-ordered fp16 (Q and K
// fused in one launch; Q pre-scaled by INV_TEMP).
// A wave's 32x32x16 fragment for (rb, ks) is the contiguous 1 KB at chunk
// (rb*32+ks)*64 + lane -> perfectly coalesced stream.
// ---------------------------------------------------------------------------
__global__ __launch_bounds__(256)
void pack_f16(const float* __restrict__ Q, const float* __restrict__ K,
              _Float16* __restrict__ Pq, _Float16* __restrict__ Pk,
              int qunits, int totunits)
{
    const int wunit = blockIdx.x * 4 + (threadIdx.x >> 6);
    if (wunit >= totunits) return;
    const bool isq = (wunit < qunits);
    const int u = isq ? wunit : wunit - qunits;
    const float* X = isq ? Q : K;
    _Float16* P = isq ? Pq : Pk;
    const float scale = isq ? INV_TEMP : 1.0f;
    const int rb = u >> 5, ks = u & 31;
    const int lane = threadIdx.x & 63;
    const int hi = lane >> 5, lx = lane & 31;
    const int row = rb * 32 + lx;
    const float4* src = (const float4*)(X + (size_t)row * D_DIM + ks * 16 + hi * 8);
    float4 v0 = src[0], v1 = src[1];
    f16x8 o;
    o[0] = (_Float16)(v0.x * scale); o[1] = (_Float16)(v0.y * scale);
    o[2] = (_Float16)(v0.z * scale); o[3] = (_Float16)(v0.w * scale);
    o[4] = (_Float16)(v1.x * scale); o[5] = (_Float16)(v1.y * scale);
    o[6] = (_Float16)(v1.z * scale); o[7] = (_Float16)(v1.w * scale);
    ((f16x8*)P)[(size_t)u * 64 + lane] = o;
}

// ---------------------------------------------------------------------------
// LDS-free, barrier-free swapped fp16 MFMA GEMM: scores^T = MFMA(K, Q).
// Depth-4 rotating pipeline: 4 fragment sets R/S/T/U in flight; set s is
// consumed at step ks and reloaded for ks+4 -> each set's loads have a
// 4-phase latency window (no copies, counted vmcnt by the compiler).
// setprio(1) around MFMA quartets (independent-wave regime).
// Lane axis = Q-row, reg pattern = K-col -> pure in-lane epilogue.
// 128(K) x 128(Q) tile, 4 waves (2 wr x 2 wc), acc[2][2] f32x16.
// Grid (64 kTiles, 32 qTiles), block 256.
// ---------------------------------------------------------------------------
#define MFMA_QUARTET(A0, A1, B0, B1)                                            \
    __builtin_amdgcn_s_setprio(1);                                              \
    acc[0][0] = __builtin_amdgcn_mfma_f32_32x32x16_f16(A0, B0, acc[0][0], 0, 0, 0); \
    acc[0][1] = __builtin_amdgcn_mfma_f32_32x32x16_f16(A0, B1, acc[0][1], 0, 0, 0); \
    acc[1][0] = __builtin_amdgcn_mfma_f32_32x32x16_f16(A1, B0, acc[1][0], 0, 0, 0); \
    acc[1][1] = __builtin_amdgcn_mfma_f32_32x32x16_f16(A1, B1, acc[1][1], 0, 0, 0); \
    __builtin_amdgcn_s_setprio(0);

__global__ __launch_bounds__(256)
void scores_mfma(const _Float16* __restrict__ Qp, const _Float16* __restrict__ Kp,
                 const int* __restrict__ ign, float4* __restrict__ part)
{
    const int tid = threadIdx.x;          // 0..255
    const int lane = tid & 63;
    const int wave = tid >> 6;            // 0..3
    const int wr = wave >> 1, wc = wave & 1;
    const int hi = lane >> 5, lx = lane & 31;
    const int bx = blockIdx.x;            // K-tile (128 rows), 0..63
    const int by = blockIdx.y;            // Q-tile (128 rows), 0..31

    const f16x8* Kp8 = (const f16x8*)Kp;
    const f16x8* Qp8 = (const f16x8*)Qp;
    const f16x8* A0p = Kp8 + ((size_t)(bx * 4 + wr * 2 + 0) * 32) * 64 + lane;
    const f16x8* A1p = Kp8 + ((size_t)(bx * 4 + wr * 2 + 1) * 32) * 64 + lane;
    const f16x8* B0p = Qp8 + ((size_t)(by * 4 + wc * 2 + 0) * 32) * 64 + lane;
    const f16x8* B1p = Qp8 + ((size_t)(by * 4 + wc * 2 + 1) * 32) * 64 + lane;

    f32x16 acc[2][2];
#pragma unroll
    for (int i = 0; i < 2; ++i)
#pragma unroll
        for (int j = 0; j < 2; ++j) acc[i][j] = (f32x16)0.f;

    // prologue: sets for ks = 0 (R), 1 (S), 2 (T), 3 (U)
    f16x8 rA0 = A0p[0],   rA1 = A1p[0],   rB0 = B0p[0],   rB1 = B1p[0];
    f16x8 sA0 = A0p[64],  sA1 = A1p[64],  sB0 = B0p[64],  sB1 = B1p[64];
    f16x8 tA0 = A0p[128], tA1 = A1p[128], tB0 = B0p[128], tB1 = B1p[128];
    f16x8 uA0 = A0p[192], uA1 = A1p[192], uB0 = B0p[192], uB1 = B1p[192];

    for (int ks = 0; ks < 32; ks += 4) {
        MFMA_QUARTET(rA0, rA1, rB0, rB1)
        if (ks + 4 < 32) {
            const int o = (ks + 4) * 64;
            rA0 = A0p[o]; rA1 = A1p[o]; rB0 = B0p[o]; rB1 = B1p[o];
        }
        MFMA_QUARTET(sA0, sA1, sB0, sB1)
        if (ks + 5 < 32) {
            const int o = (ks + 5) * 64;
            sA0 = A0p[o]; sA1 = A1p[o]; sB0 = B0p[o]; sB1 = B1p[o];
        }
        MFMA_QUARTET(tA0, tA1, tB0, tB1)
        if (ks + 6 < 32) {
            const int o = (ks + 6) * 64;
            tA0 = A0p[o]; tA1 = A1p[o]; tB0 = B0p[o]; tB1 = B1p[o];
        }
        MFMA_QUARTET(uA0, uA1, uB0, uB1)
        if (ks + 7 < 32) {
            const int o = (ks + 7) * 64;
            uA0 = A0p[o]; uA1 = A1p[o]; uB0 = B0p[o]; uB1 = B1p[o];
        }
    }

    // Epilogue (all in-lane, R11-verified):
    //   acc[i][j][r] = score(qrow = by*128 + wc*64 + j*32 + lx,
    //                        kcol = bx*128 + wr*64 + i*32 + (r&3)+8*(r>>2)+4*hi)
    const int kbase = bx * 128 + wr * 64 + 4 * hi;
    const int chunk = bx * 4 + wr * 2 + hi;       // 0..255
#pragma unroll
    for (int j = 0; j < 2; ++j) {
        const int qrow = by * 128 + wc * 64 + j * 32 + lx;
        const int4 ig = ((const int4*)ign)[qrow];   // 4 ignore indices, 16B
        float bm = -INFINITY; int bi = 0x7fffffff;
#pragma unroll
        for (int i = 0; i < 2; ++i) {
#pragma unroll
            for (int r = 0; r < 16; ++r) {
                const int col = kbase + i * 32 + (r & 3) + 8 * (r >> 2);
                float x = acc[i][j][r];
                if (col == ig.x || col == ig.y || col == ig.z || col == ig.w)
                    x = -INFINITY;
                acc[i][j][r] = x;
                if (x > bm || (x == bm && col < bi)) { bm = x; bi = col; }
            }
        }
        float se = 0.f;
#pragma unroll
        for (int i = 0; i < 2; ++i)
#pragma unroll
            for (int r = 0; r < 16; ++r)
                se += __expf(acc[i][j][r] - bm);
        part[(size_t)qrow * NCHUNK + chunk] =
            make_float4(bm, se, __int_as_float(bi), 0.f);
    }
}

// ---------------------------------------------------------------------------
// Kernel B: 4 rows per 256-thread block (one wave per row).  Merge 256
// chunk partials -> lse + argmax; positives recomputed EXACTLY in fp32
// (with duplicate dedup).
// ---------------------------------------------------------------------------
__global__ __launch_bounds__(256)
void combine_kernel(const float4* __restrict__ part,
                    const float* __restrict__ Q, const float* __restrict__ K,
                    const int* __restrict__ pos,
                    float* __restrict__ logp, float* __restrict__ corrects)
{
    const int row = blockIdx.x * 4 + (threadIdx.x >> 6);
    const int lane = threadIdx.x & 63;

    float4 p0 = part[(size_t)row * NCHUNK + lane];
    float m = p0.x, s = p0.y, av = p0.x;
    int ai = __float_as_int(p0.z);
#pragma unroll
    for (int k = 1; k < 4; ++k) {
        float4 p = part[(size_t)row * NCHUNK + k * 64 + lane];
        int oi = __float_as_int(p.z);
        float nm = fmaxf(m, p.x);
        s = s * expf(m - nm) + p.y * expf(p.x - nm);
        m = nm;
        if (p.x > av || (p.x == av && oi < ai)) { av = p.x; ai = oi; }
    }

#pragma unroll
    for (int off = 32; off >= 1; off >>= 1) {
        float om = __shfl_xor(m, off);
        float os = __shfl_xor(s, off);
        float oav = __shfl_xor(av, off);
        int oi = __shfl_xor(ai, off);
        float nm = fmaxf(m, om);
        s = s * expf(m - nm) + os * expf(om - nm);
        m = nm;
        if (oav > av || (oav == av && oi < ai)) { av = oav; ai = oi; }
    }
    float lse = m + logf(s);

    int pi[4];
#pragma unroll
    for (int p = 0; p < 4; ++p) pi[p] = pos[row * P_IDX + p];

    // positive dot-products in exact fp32: lane covers 8 consecutive d-elements
    const float4* q4 = (const float4*)(Q + (size_t)row * D_DIM);
    float4 qa = q4[lane * 2], qb = q4[lane * 2 + 1];
    float d[4];
#pragma unroll
    for (int p = 0; p < 4; ++p) {
        const float4* k4 = (const float4*)(K + (size_t)pi[p] * D_DIM);
        float4 ka = k4[lane * 2], kb = k4[lane * 2 + 1];
        d[p] = qa.x * ka.x + qa.y * ka.y + qa.z * ka.z + qa.w * ka.w
             + qb.x * kb.x + qb.y * kb.y + qb.z * kb.z + qb.w * kb.w;
    }
#pragma unroll
    for (int off = 32; off >= 1; off >>= 1) {
#pragma unroll
        for (int p = 0; p < 4; ++p) d[p] += __shfl_xor(d[p], off);
    }

    if (lane == 0) {
        float ps[4];
#pragma unroll
        for (int p = 0; p < 4; ++p) ps[p] = d[p] * INV_TEMP;
        const bool v1 = (pi[1] != pi[0]);
        const bool v2 = (pi[2] != pi[0]) && (pi[2] != pi[1]);
        const bool v3 = (pi[3] != pi[0]) && (pi[3] != pi[1]) && (pi[3] != pi[2]);
        float pm = ps[0];
        if (v1) pm = fmaxf(pm, ps[1]);
        if (v2) pm = fmaxf(pm, ps[2]);
        if (v3) pm = fmaxf(pm, ps[3]);
        float pse = expf(ps[0] - pm);
        if (v1) pse += expf(ps[1] - pm);
        if (v2) pse += expf(ps[2] - pm);
        if (v3) pse += expf(ps[3] - pm);
        float pos_lse = pm + logf(pse);
        logp[row] = pos_lse - lse;
        bool corr = (ai == pi[0]) || (ai == pi[1]) || (ai == pi[2]) || (ai == pi[3]);
        corrects[row] = corr ? 1.0f : 0.0f;
    }
}

// ---------------------------------------------------------------------------
// Kernel C: deterministic fixed-order reduction of logp -> loss
// ---------------------------------------------------------------------------
__global__ __launch_bounds__(256)
void loss_kernel(const float* __restrict__ logp, float* __restrict__ out)
{
    __shared__ float sm[256];
    const int t = threadIdx.x;
    float s = 0.f;
    for (int i = t; i < N_Q; i += 256) s += logp[i];
    sm[t] = s;
    __syncthreads();
    for (int off = 128; off >= 1; off >>= 1) {
        if (t < off) sm[t] += sm[t + off];
        __syncthreads();
    }
    if (t == 0) out[0] = -sm[0];
}

// ---------------------------------------------------------------------------
extern "C" void kernel_launch(void* const* d_in, const int* in_sizes, int n_in,
                              void* d_out, int out_size, void* d_ws, size_t ws_size,
                              hipStream_t stream)
{
    const float* Q = (const float*)d_in[0];
    const float* K = (const float*)d_in[1];
    const int* pos = (const int*)d_in[2];
    const int* ign = (const int*)d_in[3];
    float* out = (float*)d_out;

    // workspace layout (total ~28 MB)
    _Float16* Qp = (_Float16*)d_ws;                              // 4 MB
    _Float16* Kp = Qp + (size_t)N_Q * D_DIM;                     // 8 MB
    float4* part = (float4*)(Kp + (size_t)M_K * D_DIM);          // 16 MB
    float* logp = (float*)(part + (size_t)N_Q * NCHUNK);         // 16 KB

    const int qunits = N_Q / 32 * 32;     // 4096
    const int totunits = qunits + M_K / 32 * 32;   // 12288
    pack_f16<<<totunits / 4, 256, 0, stream>>>(Q, K, Qp, Kp, qunits, totunits);

    dim3 gridA(M_K / 128, N_Q / 128);   // 64 kTiles x 32 qTiles
    scores_mfma<<<gridA, 256, 0, stream>>>(Qp, Kp, ign, part);
    combine_kernel<<<N_Q / 4, 256, 0, stream>>>(part, Q, K, pos, logp, out + 1);
    loss_kernel<<<1, 256, 0, stream>>>(logp, out);
}